// Round 23
// baseline (104.844 us; speedup 1.0000x reference)
//
#include <hip/hip_runtime.h>
#include <math.h>
#include <utility>

#define BATCH 16384
#define INPUT_DIM 512
#define HIDDEN 1024
#define NROT 32
#define NANG 496   // 32*31/2

typedef _Float16 half8 __attribute__((ext_vector_type(8)));
typedef _Float16 half4 __attribute__((ext_vector_type(4)));
typedef float    f32x4 __attribute__((ext_vector_type(4)));
typedef float    f32x2 __attribute__((ext_vector_type(2)));

// ---------------------------------------------------------------------------
// Prep: W1, W2 -> f16 (x is now converted inside GEMM1's staging).
// W2 zero-padded 496 -> 512 rows.
// ---------------------------------------------------------------------------
#define NW18 (HIDDEN * INPUT_DIM / 8)    // 65536
#define NW28 (512 * HIDDEN / 8)          // 65536 (padded)

__global__ __launch_bounds__(256) void prep_w16(
    const float* __restrict__ W1, const float* __restrict__ W2,
    _Float16* __restrict__ W116, _Float16* __restrict__ W216)
{
    const int i = blockIdx.x * 256 + threadIdx.x;
    const float* src; _Float16* dst; int j; bool zero = false;
    if (i < NW18)             { j = i;          src = W1; dst = W116; }
    else if (i < NW18 + NW28) {
        j = i - NW18;           src = W2; dst = W216;
        zero = (j * 8 >= NANG * HIDDEN);
    } else return;

    half8 h;
    if (zero) {
        #pragma unroll
        for (int q = 0; q < 8; ++q) h[q] = (_Float16)0.f;
    } else {
        const float4* s = (const float4*)src + (size_t)j * 2;
        const float4 a = s[0], b = s[1];
        h[0]=(_Float16)a.x; h[1]=(_Float16)a.y; h[2]=(_Float16)a.z; h[3]=(_Float16)a.w;
        h[4]=(_Float16)b.x; h[5]=(_Float16)b.y; h[6]=(_Float16)b.z; h[7]=(_Float16)b.w;
    }
    *(half8*)(dst + (size_t)j * 8) = h;
}

// ---------------------------------------------------------------------------
// f16 MFMA GEMM (NT), XCD-local remap.
//   AF32=true: A is f32 in HBM; staged via reg-load + cvt + ds_write (fuses
//   x's f32->f16 conversion into GEMM1 -> kills prep's 50MB x round-trip).
//   AF32=false: A is f16, staged via global_load_lds (R19+ proven path).
//   B always f16 via global_load_lds with pre-swizzled source.
// ---------------------------------------------------------------------------
__device__ __forceinline__ void gld16(const void* g, void* l) {
    __builtin_amdgcn_global_load_lds(
        (const __attribute__((address_space(1))) void*)g,
        (__attribute__((address_space(3))) void*)l, 16, 0, 0);
}

template<int EPI, bool AF32>
__global__ __launch_bounds__(256) void gemm_nt_f16(
    const void* __restrict__ Av, const _Float16* __restrict__ B,
    const float* __restrict__ bias, float* __restrict__ Cf,
    _Float16* __restrict__ Ch, int M, int K, int Nout, int GX)
{
    constexpr int BK = 32;
    __shared__ _Float16 sA[2][128 * BK];
    __shared__ _Float16 sB[2][128 * BK];

    const _Float16* A16 = (const _Float16*)Av;
    const float*    A32 = (const float*)Av;

    const int g  = blockIdx.x;
    const int my = (g & 7) + (((g >> 3) / GX) << 3);
    const int mx = (g >> 3) % GX;
    const int m0 = my * 128;
    const int n0 = mx * 128;

    const int tid  = threadIdx.x;
    const int lane = tid & 63;
    const int wid  = tid >> 6;

    const int srow = lane >> 2;                 // row within 16-row segment
    const int sc   = lane & 3;                  // unswizzled 8-elem chunk
    const int schk = sc ^ (srow & 3);           // swizzled chunk

    // B (f16, pre-swizzled source, linear LDS dest)
    const _Float16* gB0 = B + (size_t)(n0 + wid * 32 + srow) * K + schk * 8;
    const _Float16* gB1 = gB0 + (size_t)16 * K;
    // A f16 path
    const _Float16* gA0 = A16 + (size_t)(m0 + wid * 32 + srow) * K + schk * 8;
    const _Float16* gA1 = gA0 + (size_t)16 * K;
    // A f32 path (unswizzled source; swizzle applied at ds_write dest)
    const float* fA0 = A32 + (size_t)(m0 + wid * 32 + srow) * K + sc * 8;
    const float* fA1 = fA0 + (size_t)16 * K;

    f32x4 ar[4];

    auto stageB = [&](int kt, int buf) {
        const size_t ko = (size_t)kt * BK;
        gld16(gB0 + ko, &sB[buf][wid * 1024]);
        gld16(gB1 + ko, &sB[buf][wid * 1024 + 512]);
        if constexpr (!AF32) {
            gld16(gA0 + ko, &sA[buf][wid * 1024]);
            gld16(gA1 + ko, &sA[buf][wid * 1024 + 512]);
        }
    };
    auto loadA = [&](int kt) {
        if constexpr (AF32) {
            const size_t ko = (size_t)kt * BK;
            ar[0] = *(const f32x4*)(fA0 + ko);
            ar[1] = *(const f32x4*)(fA0 + ko + 4);
            ar[2] = *(const f32x4*)(fA1 + ko);
            ar[3] = *(const f32x4*)(fA1 + ko + 4);
        }
    };
    auto writeA = [&](int buf) {
        if constexpr (AF32) {
            half8 h0, h1;
            #pragma unroll
            for (int j = 0; j < 4; ++j) {
                h0[j] = (_Float16)ar[0][j]; h0[4 + j] = (_Float16)ar[1][j];
                h1[j] = (_Float16)ar[2][j]; h1[4 + j] = (_Float16)ar[3][j];
            }
            const int r0 = wid * 32 + srow;
            *(half8*)&sA[buf][ r0       * 32 + (schk << 3)] = h0;
            *(half8*)&sA[buf][(r0 + 16) * 32 + (schk << 3)] = h1;
        }
    };

    const int wr = wid >> 1, wc = wid & 1;
    const int fr = lane & 15, fq = lane >> 4;
    const int swR   = ((fq ^ (fr & 3)) << 3);
    const int aBase = (wr * 64 + fr) * BK + swR;
    const int bBase = (wc * 64 + fr) * BK + swR;

    f32x4 acc[4][4];
    #pragma unroll
    for (int i = 0; i < 4; ++i)
        #pragma unroll
        for (int j = 0; j < 4; ++j) acc[i][j] = (f32x4)(0.f);

    const int NT = K / BK;
    loadA(0);
    stageB(0, 0);
    writeA(0);
    __syncthreads();
    int cur = 0;

    for (int kt = 0; kt < NT; ++kt) {
        const bool more = (kt + 1 < NT);
        if (more) { loadA(kt + 1); stageB(kt + 1, cur ^ 1); }

        half8 a_[4], b_[4];
        #pragma unroll
        for (int f = 0; f < 4; ++f) {
            a_[f] = *(const half8*)&sA[cur][aBase + f * 16 * BK];
            b_[f] = *(const half8*)&sB[cur][bBase + f * 16 * BK];
        }
        #pragma unroll
        for (int fm = 0; fm < 4; ++fm)
            #pragma unroll
            for (int fn = 0; fn < 4; ++fn)
                acc[fm][fn] = __builtin_amdgcn_mfma_f32_16x16x32_f16(
                    a_[fm], b_[fn], acc[fm][fn], 0, 0, 0);

        if (more) writeA(cur ^ 1);   // buf^1's readers finished at prev barrier
        __syncthreads();
        cur ^= 1;
    }

    if (EPI == 0) {
        #pragma unroll
        for (int fn = 0; fn < 4; ++fn) {
            const int col = n0 + wc * 64 + fn * 16 + fr;
            const float bv = bias[col];
            #pragma unroll
            for (int fm = 0; fm < 4; ++fm) {
                const int row0 = m0 + wr * 64 + fm * 16 + fq * 4;
                #pragma unroll
                for (int r = 0; r < 4; ++r)
                    Ch[(size_t)(row0 + r) * Nout + col] =
                        (_Float16)fmaxf(acc[fm][fn][r] + bv, 0.f);
            }
        }
    } else {
        #pragma unroll
        for (int fn = 0; fn < 4; ++fn) {
            const int col = n0 + wc * 64 + fn * 16 + fr;
            if (col < Nout) {
                const float bv = bias[col];
                #pragma unroll
                for (int fm = 0; fm < 4; ++fm) {
                    const int row0 = m0 + wr * 64 + fm * 16 + fq * 4;
                    #pragma unroll
                    for (int r = 0; r < 4; ++r)
                        Cf[(size_t)(row0 + r) * Nout + col] = acc[fm][fn][r] + bv;
                }
            }
        }
    }
}

// ---------------------------------------------------------------------------
// Rotate — R22 pk-chain + tree, slot index TRANSPOSED to (w*4+b):
//   chain ds_read_b128 has 4 addresses (one/batch); old spacing 4*520 f32
//   = 0 mod 32 banks -> every read 4-way conflicted (the invariant 4M
//   conflict cycles). New spacing 520 f32 = 8 banks -> addresses land on
//   disjoint bank quads {4g,4g+8,4g+16,4g+24}: chain reads conflict-free.
//   Slot map: factor/cs slot (w*4+b); PCM_pi -> slot (pi*4+b); R f32 flat
//   over slots 8..15 at 8*520 + ba*1032 (spacing = 8 banks). Math identical.
// ---------------------------------------------------------------------------
struct IJTbl { unsigned char i[NANG]; unsigned char j[NANG]; };
constexpr IJTbl make_ij_tbl() {
    IJTbl t{};
    int k = 0;
    for (int i = 0; i < NROT - 1; ++i)
        for (int j = i + 1; j < NROT; ++j) { t.i[k] = (unsigned char)i; t.j[k] = (unsigned char)j; ++k; }
    return t;
}
constexpr IJTbl IJT = make_ij_tbl();

#define SLOT_H 1040   // f16 per slot (2080 B)
#define SLOT_F 520    // f32 per slot
#define R_BASE (8 * SLOT_F)   // f32 base of flat R region (slots 8..15)

__device__ __forceinline__ f32x2 lo2(const f32x4 q) { return __builtin_shufflevector(q, q, 0, 1); }
__device__ __forceinline__ f32x2 hi2(const f32x4 q) { return __builtin_shufflevector(q, q, 2, 3); }

template<int K, bool REV>
__device__ __forceinline__ void rot1pk(const f32x2 p, f32x2 (&v)[NROT]) {
    constexpr int i = IJT.i[K], j = IJT.j[K];
    f32x2 t0, t1, ni, nj;
    asm("v_pk_mul_f32 %0, %1, %2 op_sel:[1,0] op_sel_hi:[1,1]"
        : "=v"(t0) : "v"(p), "v"(v[j]));
    asm("v_pk_mul_f32 %0, %1, %2 op_sel:[1,0] op_sel_hi:[1,1]"
        : "=v"(t1) : "v"(p), "v"(v[i]));
    if constexpr (!REV) {
        asm("v_pk_fma_f32 %0, %1, %2, %3 op_sel:[0,0,0] op_sel_hi:[0,1,1]"
            : "=v"(ni) : "v"(p), "v"(v[i]), "v"(t0));
        asm("v_pk_fma_f32 %0, %1, %2, %3 op_sel:[0,0,0] op_sel_hi:[0,1,1] neg_lo:[0,0,1] neg_hi:[0,0,1]"
            : "=v"(nj) : "v"(p), "v"(v[j]), "v"(t1));
    } else {
        asm("v_pk_fma_f32 %0, %1, %2, %3 op_sel:[0,0,0] op_sel_hi:[0,1,1] neg_lo:[0,0,1] neg_hi:[0,0,1]"
            : "=v"(ni) : "v"(p), "v"(v[i]), "v"(t0));
        asm("v_pk_fma_f32 %0, %1, %2, %3 op_sel:[0,0,0] op_sel_hi:[0,1,1]"
            : "=v"(nj) : "v"(p), "v"(v[j]), "v"(t1));
    }
    v[i] = ni; v[j] = nj;
}

template<int W, int T>
__device__ __forceinline__ void chain_step(const float* __restrict__ lcs,
                                           f32x2 (&v)[NROT]) {
    if constexpr ((W & 1) == 0) {
        constexpr int g = T;
        constexpr int K0 = 124 * W + 2 * g;
        const f32x4 q = *(const f32x4*)(lcs + g * 4);
        rot1pk<K0,     false>(lo2(q), v);
        rot1pk<K0 + 1, false>(hi2(q), v);
    } else {
        constexpr int g = 61 - T;
        constexpr int K0 = 124 * W + 2 * g;
        const f32x4 q = *(const f32x4*)(lcs + g * 4);
        rot1pk<K0 + 1, true>(hi2(q), v);
        rot1pk<K0,     true>(lo2(q), v);
    }
}

template<int W, size_t... Ts>
__device__ __forceinline__ void chain_runW(const float* __restrict__ lcs,
                                           f32x2 (&v)[NROT],
                                           std::index_sequence<Ts...>) {
    (chain_step<W, (int)Ts>(lcs, v), ...);
}

template<int W>
__device__ __forceinline__ void chain_and_store(float* __restrict__ smemf,
                                                _Float16* __restrict__ lh,
                                                int b, int rp) {
    const float* lcs = smemf + (W * 4 + b) * SLOT_F;   // cs in own slot

    f32x2 v[NROT];
    #pragma unroll
    for (int c = 0; c < NROT; ++c) {
        f32x2 iv;
        iv[0] = (c == rp)      ? 1.f : 0.f;
        iv[1] = (c == rp + 16) ? 1.f : 0.f;
        v[c] = iv;
    }
    chain_runW<W>(lcs, v, std::make_index_sequence<62>{});

    const int base = (W * 4 + b) * SLOT_H;   // factor overwrites own slot
    #pragma unroll
    for (int kq = 0; kq < 4; ++kq) {
        half8 h0, h1;
        #pragma unroll
        for (int j = 0; j < 8; ++j) {
            h0[j] = (_Float16)v[kq * 8 + j][0];
            h1[j] = (_Float16)v[kq * 8 + j][1];
        }
        const int sw = (kq ^ (rp & 3)) << 3;
        *(half8*)&lh[base +  rp       * 32 + sw] = h0;
        *(half8*)&lh[base + (rp + 16) * 32 + sw] = h1;
    }
}

__global__ __launch_bounds__(256) void rotate_kernel(
    const float* __restrict__ theta, float* __restrict__ out)
{
    __shared__ float smem[16 * SLOT_F];   // 33,280 B
    _Float16* lh = (_Float16*)smem;

    const int tid  = threadIdx.x;
    const int wid  = tid >> 6;             // 0..3 = chunk
    const int lane = tid & 63;
    const int lb   = lane >> 4;            // batch within block (0..3)
    const int rp   = lane & 15;            // row pair: rows rp, rp+16
    const int fr = lane & 15, fq = lane >> 4;
    const size_t b0 = (size_t)blockIdx.x * 4;

    // ---- stage: theta -> sincos -> (c,s) into slot (chunk, b) ----
    #pragma unroll
    for (int it = 0; it < 2; ++it) {
        const int t = it * 256 + tid;
        if (t < 496) {
            const int b    = t / 124;
            const int idx  = t - b * 124;
            const int w    = idx / 31;
            const int lidx = idx - 31 * w;
            const f32x4 th = *(const f32x4*)(theta + (b0 + b) * NANG + idx * 4);
            f32x4 p0, p1;
            float s, c;
            __sincosf(th[0], &s, &c); p0[0] = c; p0[1] = s;
            __sincosf(th[1], &s, &c); p0[2] = c; p0[3] = s;
            __sincosf(th[2], &s, &c); p1[0] = c; p1[1] = s;
            __sincosf(th[3], &s, &c); p1[2] = c; p1[3] = s;
            const int base = (w * 4 + b) * SLOT_F + lidx * 8;
            *(f32x4*)&smem[base]     = p0;
            *(f32x4*)&smem[base + 4] = p1;
        }
    }
    __syncthreads();

    // ---- chunk chains: wave w = chunk w; lane -> (batch, row-pair) ----
    if      (wid == 0) chain_and_store<0>(smem, lh, lb, rp);
    else if (wid == 1) chain_and_store<1>(smem, lh, lb, rp);
    else if (wid == 2) chain_and_store<2>(smem, lh, lb, rp);
    else               chain_and_store<3>(smem, lh, lb, rp);
    __syncthreads();

    // ---- L1: wave = batch ba ----
    //  C_w lives in slot (w*4+ba). pi=0: mfma(C1^T, C0) = P0^T -> col-major
    //  store -> PCM0 = P0 rows (slot ba); pi=1: mfma(C2, C3^T) = P1 ->
    //  PCM1 = P1^T rows (slot 4+ba).
    {
        const int ba = wid;
        const int swz = (fq ^ (fr & 3)) << 3;
        half8 a[2][2], b[2][2];
        #pragma unroll
        for (int pi = 0; pi < 2; ++pi) {
            const int Asl = (pi == 0) ? (4 + ba)  : (8 + ba);    // C1 / C2
            const int Bsl = (pi == 0) ? (ba)      : (12 + ba);   // C0 / C3
            #pragma unroll
            for (int mi = 0; mi < 2; ++mi) {
                a[pi][mi] = *(const half8*)&lh[Asl * SLOT_H + (mi * 16 + fr) * 32 + swz];
                b[pi][mi] = *(const half8*)&lh[Bsl * SLOT_H + (mi * 16 + fr) * 32 + swz];
            }
        }
        f32x4 d[2][2][2];
        #pragma unroll
        for (int pi = 0; pi < 2; ++pi)
            #pragma unroll
            for (int mi = 0; mi < 2; ++mi)
                #pragma unroll
                for (int ni = 0; ni < 2; ++ni)
                    d[pi][mi][ni] = __builtin_amdgcn_mfma_f32_16x16x32_f16(
                        a[pi][mi], b[pi][ni], (f32x4)(0.f), 0, 0, 0);
        __syncthreads();   // all factor reads complete before PCM overlay
        #pragma unroll
        for (int pi = 0; pi < 2; ++pi) {
            const int Pb = (pi * 4 + ba) * SLOT_H;
            #pragma unroll
            for (int mi = 0; mi < 2; ++mi)
                #pragma unroll
                for (int ni = 0; ni < 2; ++ni) {
                    half4 hv;
                    #pragma unroll
                    for (int q = 0; q < 4; ++q) hv[q] = (_Float16)d[pi][mi][ni][q];
                    const int col  = ni * 16 + fr;
                    const int rowb = (mi * 16 + fq * 4) ^ ((col & 3) << 3);
                    *(half4*)&lh[Pb + col * 32 + rowb] = hv;
                }
        }
    }
    __syncthreads();

    // ---- L2: wave = batch ba; mfma(PCM1, PCM0) = P1^T @ P0^T = R^T ----
    //  R f32 flat over slots 8..15 (old C2/C3, dead after L1 barrier).
    {
        const int ba = wid;
        const int Ab = (4 + ba) * SLOT_H;   // P1^T rows
        const int Bb = (ba)     * SLOT_H;   // P0 rows
        const int Rb = R_BASE + ba * 1032;
        const int swz = (fq ^ (fr & 3)) << 3;
        #pragma unroll
        for (int mi = 0; mi < 2; ++mi) {
            const half8 a = *(const half8*)&lh[Ab + (mi * 16 + fr) * 32 + swz];
            #pragma unroll
            for (int ni = 0; ni < 2; ++ni) {
                const half8 b = *(const half8*)&lh[Bb + (ni * 16 + fr) * 32 + swz];
                const f32x4 d = __builtin_amdgcn_mfma_f32_16x16x32_f16(
                    a, b, (f32x4)(0.f), 0, 0, 0);
                const int row  = ni * 16 + fr;
                const int colq = mi * 4 + fq;
                *(f32x4*)&smem[Rb + row * 32 + ((colq ^ (row & 7)) << 2)] = d;
            }
        }
    }
    __syncthreads();

    // ---- coalesced copy-out: 4 batches x 256 f4 ----
    #pragma unroll
    for (int s = 0; s < 4; ++s) {
        const int idx = s * 256 + tid;
        const int ba  = idx >> 8;
        const int f4i = idx & 255;
        const int row = f4i >> 3;
        const int cc  = f4i & 7;
        const f32x4 val =
            *(const f32x4*)&smem[R_BASE + ba * 1032 + row * 32 + ((cc ^ (row & 7)) << 2)];
        *(f32x4*)(out + (b0 + ba) * 1024 + (size_t)f4i * 4) = val;
    }
}

// ---------------------------------------------------------------------------
extern "C" void kernel_launch(void* const* d_in, const int* in_sizes, int n_in,
                              void* d_out, int out_size, void* d_ws, size_t ws_size,
                              hipStream_t stream)
{
    const float* x  = (const float*)d_in[0];   // [16384, 512]
    const float* W1 = (const float*)d_in[1];   // [1024, 512]
    const float* b1 = (const float*)d_in[2];   // [1024]
    const float* W2 = (const float*)d_in[3];   // [496, 1024]
    const float* b2 = (const float*)d_in[4];   // [496]
    float* out = (float*)d_out;                // [16384, 32, 32]

    _Float16* h16  = (_Float16*)d_out;                    // 33.55 MB
    _Float16* W116 = h16  + (size_t)BATCH * HIDDEN;       // 1 MB
    _Float16* W216 = W116 + (size_t)HIDDEN * INPUT_DIM;   // 1 MB (512-row pad)
    float*    th   = (float*)d_ws;                        // theta f32

    // prep: W1, W2(padded) -> f16 (x handled inside GEMM1)
    prep_w16<<<dim3((NW18 + NW28) / 256), 256, 0, stream>>>(W1, W2, W116, W216);

    // h16 = f16(relu(x @ W1^T + b1)); A = x f32 (fused cvt staging)
    gemm_nt_f16<0, true><<<dim3(8 * 128), 256, 0, stream>>>(
        x, W116, b1, nullptr, h16, BATCH, INPUT_DIM, HIDDEN, 8);

    // th = h16 @ W2^T + b2; A = h16 f16 (global_load_lds path)
    gemm_nt_f16<1, false><<<dim3(4 * 128), 256, 0, stream>>>(
        h16, W216, b2, th, nullptr, BATCH, HIDDEN, NANG, 4);

    rotate_kernel<<<dim3(BATCH / 4), 256, 0, stream>>>(th, out);
}

// Round 24
// 104.243 us; speedup vs baseline: 1.0058x; 1.0058x over previous
//
#include <hip/hip_runtime.h>
#include <math.h>
#include <utility>

#define BATCH 16384
#define INPUT_DIM 512
#define HIDDEN 1024
#define NROT 32
#define NANG 496   // 32*31/2

typedef _Float16 half8 __attribute__((ext_vector_type(8)));
typedef _Float16 half4 __attribute__((ext_vector_type(4)));
typedef float    f32x4 __attribute__((ext_vector_type(4)));
typedef float    f32x2 __attribute__((ext_vector_type(2)));

// ---------------------------------------------------------------------------
// Fused prep: x, W1, W2 -> f16 in one launch (R22 passing version; the R23
// GEMM-fused x conversion regressed GEMM1 24->58us and is reverted).
// ---------------------------------------------------------------------------
#define NX8  (BATCH * INPUT_DIM / 8)
#define NW18 (HIDDEN * INPUT_DIM / 8)
#define NW28 (512 * HIDDEN / 8)

__global__ __launch_bounds__(256) void prep_f16(
    const float* __restrict__ x, const float* __restrict__ W1,
    const float* __restrict__ W2, _Float16* __restrict__ x16,
    _Float16* __restrict__ W116, _Float16* __restrict__ W216)
{
    const int i = blockIdx.x * 256 + threadIdx.x;
    const float* src; _Float16* dst; int j; bool zero = false;
    if (i < NX8)              { j = i;               src = x;  dst = x16;  }
    else if (i < NX8 + NW18)  { j = i - NX8;         src = W1; dst = W116; }
    else if (i < NX8 + NW18 + NW28) {
        j = i - NX8 - NW18;   src = W2; dst = W216;
        zero = (j * 8 >= NANG * HIDDEN);
    } else return;

    half8 h;
    if (zero) {
        #pragma unroll
        for (int q = 0; q < 8; ++q) h[q] = (_Float16)0.f;
    } else {
        const float4* s = (const float4*)src + (size_t)j * 2;
        const float4 a = s[0], b = s[1];
        h[0]=(_Float16)a.x; h[1]=(_Float16)a.y; h[2]=(_Float16)a.z; h[3]=(_Float16)a.w;
        h[4]=(_Float16)b.x; h[5]=(_Float16)b.y; h[6]=(_Float16)b.z; h[7]=(_Float16)b.w;
    }
    *(half8*)(dst + (size_t)j * 8) = h;
}

// ---------------------------------------------------------------------------
// f16 MFMA GEMM (NT), global_load_lds staging + XCD-local remap (R22 passing)
// ---------------------------------------------------------------------------
__device__ __forceinline__ void gld16(const void* g, void* l) {
    __builtin_amdgcn_global_load_lds(
        (const __attribute__((address_space(1))) void*)g,
        (__attribute__((address_space(3))) void*)l, 16, 0, 0);
}

template<int EPI>
__global__ __launch_bounds__(256) void gemm_nt_f16(
    const _Float16* __restrict__ A, const _Float16* __restrict__ B,
    const float* __restrict__ bias, float* __restrict__ Cf,
    _Float16* __restrict__ Ch, int M, int K, int Nout, int GX)
{
    constexpr int BK = 32;
    __shared__ _Float16 sA[2][128 * BK];
    __shared__ _Float16 sB[2][128 * BK];

    const int g  = blockIdx.x;
    const int my = (g & 7) + (((g >> 3) / GX) << 3);
    const int mx = (g >> 3) % GX;
    const int m0 = my * 128;
    const int n0 = mx * 128;

    const int tid  = threadIdx.x;
    const int lane = tid & 63;
    const int wid  = tid >> 6;

    const int srow = lane >> 2;
    const int schk = (lane & 3) ^ (srow & 3);
    const _Float16* gA0 = A + (size_t)(m0 + wid * 32 + srow) * K + schk * 8;
    const _Float16* gA1 = gA0 + (size_t)16 * K;
    const _Float16* gB0 = B + (size_t)(n0 + wid * 32 + srow) * K + schk * 8;
    const _Float16* gB1 = gB0 + (size_t)16 * K;

    auto stage = [&](int kt, int buf) {
        const size_t ko = (size_t)kt * BK;
        gld16(gA0 + ko, &sA[buf][wid * 1024]);
        gld16(gA1 + ko, &sA[buf][wid * 1024 + 512]);
        gld16(gB0 + ko, &sB[buf][wid * 1024]);
        gld16(gB1 + ko, &sB[buf][wid * 1024 + 512]);
    };

    const int wr = wid >> 1, wc = wid & 1;
    const int fr = lane & 15, fq = lane >> 4;
    const int swR   = ((fq ^ (fr & 3)) << 3);
    const int aBase = (wr * 64 + fr) * BK + swR;
    const int bBase = (wc * 64 + fr) * BK + swR;

    f32x4 acc[4][4];
    #pragma unroll
    for (int i = 0; i < 4; ++i)
        #pragma unroll
        for (int j = 0; j < 4; ++j) acc[i][j] = (f32x4)(0.f);

    const int NT = K / BK;
    stage(0, 0);
    __syncthreads();
    int cur = 0;

    for (int kt = 0; kt < NT; ++kt) {
        if (kt + 1 < NT) stage(kt + 1, cur ^ 1);

        half8 a_[4], b_[4];
        #pragma unroll
        for (int f = 0; f < 4; ++f) {
            a_[f] = *(const half8*)&sA[cur][aBase + f * 16 * BK];
            b_[f] = *(const half8*)&sB[cur][bBase + f * 16 * BK];
        }
        #pragma unroll
        for (int fm = 0; fm < 4; ++fm)
            #pragma unroll
            for (int fn = 0; fn < 4; ++fn)
                acc[fm][fn] = __builtin_amdgcn_mfma_f32_16x16x32_f16(
                    a_[fm], b_[fn], acc[fm][fn], 0, 0, 0);

        __syncthreads();
        cur ^= 1;
    }

    if (EPI == 0) {
        #pragma unroll
        for (int fn = 0; fn < 4; ++fn) {
            const int col = n0 + wc * 64 + fn * 16 + fr;
            const float bv = bias[col];
            #pragma unroll
            for (int fm = 0; fm < 4; ++fm) {
                const int row0 = m0 + wr * 64 + fm * 16 + fq * 4;
                #pragma unroll
                for (int r = 0; r < 4; ++r)
                    Ch[(size_t)(row0 + r) * Nout + col] =
                        (_Float16)fmaxf(acc[fm][fn][r] + bv, 0.f);
            }
        }
    } else {
        #pragma unroll
        for (int fn = 0; fn < 4; ++fn) {
            const int col = n0 + wc * 64 + fn * 16 + fr;
            if (col < Nout) {
                const float bv = bias[col];
                #pragma unroll
                for (int fm = 0; fm < 4; ++fm) {
                    const int row0 = m0 + wr * 64 + fm * 16 + fq * 4;
                    #pragma unroll
                    for (int r = 0; r < 4; ++r)
                        Cf[(size_t)(row0 + r) * Nout + col] = acc[fm][fn][r] + bv;
                }
            }
        }
    }
}

// ---------------------------------------------------------------------------
// Rotate — R22/R23 pk-chain + tree, LDS trimmed to EXACTLY 32 KB:
//   slots 520 -> 512 f32 (2048 B: factor f16 = 2048 B exactly, cs 992 B
//   fits); R f32 overlays slots 8..15 flat at stride 1024 -> total
//   16*2048 = 32,768 B => 5 blocks/CU (was 4 at 33,280 B) = 20 waves/CU
//   cap, +25% latency hiding for the dependent pk chain.
//   Conflict counter (4.01M) proven layout-invariant across R19-R23 ->
//   not chased further. Math byte-identical to R21/R22 (passing).
// ---------------------------------------------------------------------------
struct IJTbl { unsigned char i[NANG]; unsigned char j[NANG]; };
constexpr IJTbl make_ij_tbl() {
    IJTbl t{};
    int k = 0;
    for (int i = 0; i < NROT - 1; ++i)
        for (int j = i + 1; j < NROT; ++j) { t.i[k] = (unsigned char)i; t.j[k] = (unsigned char)j; ++k; }
    return t;
}
constexpr IJTbl IJT = make_ij_tbl();

#define SLOT_H 1024            // f16 per slot (2048 B)
#define SLOT_F 512             // f32 per slot
#define R_BASE (8 * SLOT_F)    // f32 base of flat R region (slots 8..15)

__device__ __forceinline__ f32x2 lo2(const f32x4 q) { return __builtin_shufflevector(q, q, 0, 1); }
__device__ __forceinline__ f32x2 hi2(const f32x4 q) { return __builtin_shufflevector(q, q, 2, 3); }

template<int K, bool REV>
__device__ __forceinline__ void rot1pk(const f32x2 p, f32x2 (&v)[NROT]) {
    constexpr int i = IJT.i[K], j = IJT.j[K];
    f32x2 t0, t1, ni, nj;
    asm("v_pk_mul_f32 %0, %1, %2 op_sel:[1,0] op_sel_hi:[1,1]"
        : "=v"(t0) : "v"(p), "v"(v[j]));
    asm("v_pk_mul_f32 %0, %1, %2 op_sel:[1,0] op_sel_hi:[1,1]"
        : "=v"(t1) : "v"(p), "v"(v[i]));
    if constexpr (!REV) {
        asm("v_pk_fma_f32 %0, %1, %2, %3 op_sel:[0,0,0] op_sel_hi:[0,1,1]"
            : "=v"(ni) : "v"(p), "v"(v[i]), "v"(t0));
        asm("v_pk_fma_f32 %0, %1, %2, %3 op_sel:[0,0,0] op_sel_hi:[0,1,1] neg_lo:[0,0,1] neg_hi:[0,0,1]"
            : "=v"(nj) : "v"(p), "v"(v[j]), "v"(t1));
    } else {
        asm("v_pk_fma_f32 %0, %1, %2, %3 op_sel:[0,0,0] op_sel_hi:[0,1,1] neg_lo:[0,0,1] neg_hi:[0,0,1]"
            : "=v"(ni) : "v"(p), "v"(v[i]), "v"(t0));
        asm("v_pk_fma_f32 %0, %1, %2, %3 op_sel:[0,0,0] op_sel_hi:[0,1,1]"
            : "=v"(nj) : "v"(p), "v"(v[j]), "v"(t1));
    }
    v[i] = ni; v[j] = nj;
}

template<int W, int T>
__device__ __forceinline__ void chain_step(const float* __restrict__ lcs,
                                           f32x2 (&v)[NROT]) {
    if constexpr ((W & 1) == 0) {
        constexpr int g = T;
        constexpr int K0 = 124 * W + 2 * g;
        const f32x4 q = *(const f32x4*)(lcs + g * 4);
        rot1pk<K0,     false>(lo2(q), v);
        rot1pk<K0 + 1, false>(hi2(q), v);
    } else {
        constexpr int g = 61 - T;
        constexpr int K0 = 124 * W + 2 * g;
        const f32x4 q = *(const f32x4*)(lcs + g * 4);
        rot1pk<K0 + 1, true>(hi2(q), v);
        rot1pk<K0,     true>(lo2(q), v);
    }
}

template<int W, size_t... Ts>
__device__ __forceinline__ void chain_runW(const float* __restrict__ lcs,
                                           f32x2 (&v)[NROT],
                                           std::index_sequence<Ts...>) {
    (chain_step<W, (int)Ts>(lcs, v), ...);
}

template<int W>
__device__ __forceinline__ void chain_and_store(float* __restrict__ smemf,
                                                _Float16* __restrict__ lh,
                                                int b, int rp) {
    const float* lcs = smemf + (W * 4 + b) * SLOT_F;   // cs in own slot

    f32x2 v[NROT];
    #pragma unroll
    for (int c = 0; c < NROT; ++c) {
        f32x2 iv;
        iv[0] = (c == rp)      ? 1.f : 0.f;
        iv[1] = (c == rp + 16) ? 1.f : 0.f;
        v[c] = iv;
    }
    chain_runW<W>(lcs, v, std::make_index_sequence<62>{});

    const int base = (W * 4 + b) * SLOT_H;   // factor overwrites own slot
    #pragma unroll
    for (int kq = 0; kq < 4; ++kq) {
        half8 h0, h1;
        #pragma unroll
        for (int j = 0; j < 8; ++j) {
            h0[j] = (_Float16)v[kq * 8 + j][0];
            h1[j] = (_Float16)v[kq * 8 + j][1];
        }
        const int sw = (kq ^ (rp & 3)) << 3;
        *(half8*)&lh[base +  rp       * 32 + sw] = h0;
        *(half8*)&lh[base + (rp + 16) * 32 + sw] = h1;
    }
}

__global__ __launch_bounds__(256) void rotate_kernel(
    const float* __restrict__ theta, float* __restrict__ out)
{
    __shared__ float smem[16 * SLOT_F];   // 32,768 B exactly -> 5 blocks/CU
    _Float16* lh = (_Float16*)smem;

    const int tid  = threadIdx.x;
    const int wid  = tid >> 6;             // 0..3 = chunk
    const int lane = tid & 63;
    const int lb   = lane >> 4;            // batch within block (0..3)
    const int rp   = lane & 15;            // row pair: rows rp, rp+16
    const int fr = lane & 15, fq = lane >> 4;
    const size_t b0 = (size_t)blockIdx.x * 4;

    // ---- stage: theta -> sincos -> (c,s) into slot (chunk, b) ----
    #pragma unroll
    for (int it = 0; it < 2; ++it) {
        const int t = it * 256 + tid;
        if (t < 496) {
            const int b    = t / 124;
            const int idx  = t - b * 124;
            const int w    = idx / 31;
            const int lidx = idx - 31 * w;
            const f32x4 th = *(const f32x4*)(theta + (b0 + b) * NANG + idx * 4);
            f32x4 p0, p1;
            float s, c;
            __sincosf(th[0], &s, &c); p0[0] = c; p0[1] = s;
            __sincosf(th[1], &s, &c); p0[2] = c; p0[3] = s;
            __sincosf(th[2], &s, &c); p1[0] = c; p1[1] = s;
            __sincosf(th[3], &s, &c); p1[2] = c; p1[3] = s;
            const int base = (w * 4 + b) * SLOT_F + lidx * 8;
            *(f32x4*)&smem[base]     = p0;
            *(f32x4*)&smem[base + 4] = p1;
        }
    }
    __syncthreads();

    // ---- chunk chains: wave w = chunk w; lane -> (batch, row-pair) ----
    if      (wid == 0) chain_and_store<0>(smem, lh, lb, rp);
    else if (wid == 1) chain_and_store<1>(smem, lh, lb, rp);
    else if (wid == 2) chain_and_store<2>(smem, lh, lb, rp);
    else               chain_and_store<3>(smem, lh, lb, rp);
    __syncthreads();

    // ---- L1: wave = batch ba ----
    //  C_w lives in slot (w*4+ba). pi=0: mfma(C1^T, C0) = P0^T -> col-major
    //  store -> PCM0 = P0 rows (slot ba); pi=1: mfma(C2, C3^T) = P1 ->
    //  PCM1 = P1^T rows (slot 4+ba).
    {
        const int ba = wid;
        const int swz = (fq ^ (fr & 3)) << 3;
        half8 a[2][2], b[2][2];
        #pragma unroll
        for (int pi = 0; pi < 2; ++pi) {
            const int Asl = (pi == 0) ? (4 + ba)  : (8 + ba);    // C1 / C2
            const int Bsl = (pi == 0) ? (ba)      : (12 + ba);   // C0 / C3
            #pragma unroll
            for (int mi = 0; mi < 2; ++mi) {
                a[pi][mi] = *(const half8*)&lh[Asl * SLOT_H + (mi * 16 + fr) * 32 + swz];
                b[pi][mi] = *(const half8*)&lh[Bsl * SLOT_H + (mi * 16 + fr) * 32 + swz];
            }
        }
        f32x4 d[2][2][2];
        #pragma unroll
        for (int pi = 0; pi < 2; ++pi)
            #pragma unroll
            for (int mi = 0; mi < 2; ++mi)
                #pragma unroll
                for (int ni = 0; ni < 2; ++ni)
                    d[pi][mi][ni] = __builtin_amdgcn_mfma_f32_16x16x32_f16(
                        a[pi][mi], b[pi][ni], (f32x4)(0.f), 0, 0, 0);
        __syncthreads();   // all factor reads complete before PCM overlay
        #pragma unroll
        for (int pi = 0; pi < 2; ++pi) {
            const int Pb = (pi * 4 + ba) * SLOT_H;
            #pragma unroll
            for (int mi = 0; mi < 2; ++mi)
                #pragma unroll
                for (int ni = 0; ni < 2; ++ni) {
                    half4 hv;
                    #pragma unroll
                    for (int q = 0; q < 4; ++q) hv[q] = (_Float16)d[pi][mi][ni][q];
                    const int col  = ni * 16 + fr;
                    const int rowb = (mi * 16 + fq * 4) ^ ((col & 3) << 3);
                    *(half4*)&lh[Pb + col * 32 + rowb] = hv;
                }
        }
    }
    __syncthreads();

    // ---- L2: wave = batch ba; mfma(PCM1, PCM0) = P1^T @ P0^T = R^T ----
    //  R f32 flat over slots 8..15 (old C2/C3, dead after L1 barrier).
    {
        const int ba = wid;
        const int Ab = (4 + ba) * SLOT_H;   // P1^T rows
        const int Bb = (ba)     * SLOT_H;   // P0 rows
        const int Rb = R_BASE + ba * 1024;
        const int swz = (fq ^ (fr & 3)) << 3;
        #pragma unroll
        for (int mi = 0; mi < 2; ++mi) {
            const half8 a = *(const half8*)&lh[Ab + (mi * 16 + fr) * 32 + swz];
            #pragma unroll
            for (int ni = 0; ni < 2; ++ni) {
                const half8 b = *(const half8*)&lh[Bb + (ni * 16 + fr) * 32 + swz];
                const f32x4 d = __builtin_amdgcn_mfma_f32_16x16x32_f16(
                    a, b, (f32x4)(0.f), 0, 0, 0);
                const int row  = ni * 16 + fr;
                const int colq = mi * 4 + fq;
                *(f32x4*)&smem[Rb + row * 32 + ((colq ^ (row & 7)) << 2)] = d;
            }
        }
    }
    __syncthreads();

    // ---- coalesced copy-out: 4 batches x 256 f4 ----
    #pragma unroll
    for (int s = 0; s < 4; ++s) {
        const int idx = s * 256 + tid;
        const int ba  = idx >> 8;
        const int f4i = idx & 255;
        const int row = f4i >> 3;
        const int cc  = f4i & 7;
        const f32x4 val =
            *(const f32x4*)&smem[R_BASE + ba * 1024 + row * 32 + ((cc ^ (row & 7)) << 2)];
        *(f32x4*)(out + (b0 + ba) * 1024 + (size_t)f4i * 4) = val;
    }
}

// ---------------------------------------------------------------------------
extern "C" void kernel_launch(void* const* d_in, const int* in_sizes, int n_in,
                              void* d_out, int out_size, void* d_ws, size_t ws_size,
                              hipStream_t stream)
{
    const float* x  = (const float*)d_in[0];   // [16384, 512]
    const float* W1 = (const float*)d_in[1];   // [1024, 512]
    const float* b1 = (const float*)d_in[2];   // [1024]
    const float* W2 = (const float*)d_in[3];   // [496, 1024]
    const float* b2 = (const float*)d_in[4];   // [496]
    float* out = (float*)d_out;                // [16384, 32, 32]

    _Float16* h16  = (_Float16*)d_out;                    // 33.55 MB
    _Float16* x16  = h16  + (size_t)BATCH * HIDDEN;       // 16.78 MB
    _Float16* W116 = x16  + (size_t)BATCH * INPUT_DIM;    // 1 MB
    _Float16* W216 = W116 + (size_t)HIDDEN * INPUT_DIM;   // 1 MB (512-row pad)
    float*    th   = (float*)d_ws;                        // theta f32

    prep_f16<<<dim3((NX8 + NW18 + NW28) / 256), 256, 0, stream>>>(
        x, W1, W2, x16, W116, W216);

    gemm_nt_f16<0><<<dim3(8 * 128), 256, 0, stream>>>(
        x16, W116, b1, nullptr, h16, BATCH, INPUT_DIM, HIDDEN, 8);

    gemm_nt_f16<1><<<dim3(4 * 128), 256, 0, stream>>>(
        h16, W216, b2, th, nullptr, BATCH, HIDDEN, NANG, 4);

    rotate_kernel<<<dim3(BATCH / 4), 256, 0, stream>>>(th, out);
}